// Round 4
// baseline (476.259 us; speedup 1.0000x reference)
//
#include <hip/hip_runtime.h>

// out[b, I[e]] += inputs[b, J[e]] * W3[e] * velocity[J[e]]; out += bias
// R2: per-edge atomics = 204.8MB atomic-path traffic (bound).
// R4: bucket build + gather -> 161.7us; build dominates (scatter evictions).
// R5: nt stores FALSIFIED (WRITE rose). Reverted.
// R6: two-pass counting sort (256-row coarse + finesort) -> 159us. finesort
//     starved (196 blocks) + edges round-trip + redundant passes.
// R7: fused filter-gather, shuffle compaction: 445us. Blamed spills.
// R8: LDS compaction + broadcast: 357us. No spills (WRITE==out exactly).
// R9: atomicAdd(shared) vs unsafeAtomicAdd A/B: IDENTICAL 356us -> atomic
//     lowering falsified. Remaining delta vs fast R6 gather: 13 waves/CU
//     (vs 32) + record->addr dependency through LDS (lgkmcnt serializes
//     loads; VGPR=24 = compiler didn't keep 8 loads in flight).
// R10: kill the filter instead of fixing it. Pass-1 bins DIRECTLY at 64-row
//     granularity (NC=782). Run density kept via PCHUNK=8192 (runs ~10.5
//     rec = 84B, same as R6). Gather = verbatim R6 inner loop (records in
//     REGISTERS, __shfl broadcast, 8 in_T loads in flight) + ds_add_f32
//     into 64x65 tile; 1 block/bucket, 512 thr, 16.6KB LDS -> ~24 waves/CU;
//     part read ONCE. No finesort, no compaction, no edges array.

#define BATCH 64
#define QROWS 64              // rows per bucket == rows per gather block
#define PCHUNK 8192           // edges per hist/partition block

typedef unsigned long long ull;

// ---- K1: transpose inputs [B,N] -> in_T [N,B]; zero histogram ----
__global__ void k_prep(const float* __restrict__ in, float* __restrict__ in_T,
                       int* __restrict__ coarse_hist, int NC, int N) {
    const int gid = blockIdx.x * 256 + threadIdx.x;
    if (gid < NC) coarse_hist[gid] = 0;

    __shared__ float tile[64 * 65];
    const int n0 = blockIdx.x * 64;
    const int t  = threadIdx.x;
    const int x  = t & 63;
    const int r  = t >> 6;
    for (int b = r; b < BATCH; b += 4) {
        float v = 0.f;
        if (n0 + x < N) v = in[(size_t)b * N + n0 + x];
        tile[x * 65 + b] = v;
    }
    __syncthreads();
    for (int xr = r; xr < 64; xr += 4) {
        if (n0 + xr < N) in_T[(size_t)(n0 + xr) * BATCH + x] = tile[xr * 65 + x];
    }
}

// ---- K2: 64-row-bucket histogram (LDS-aggregated, up to 1024 bins) ----
__global__ void __launch_bounds__(1024) k_hist(const int* __restrict__ I,
                                               int* __restrict__ coarse_hist,
                                               int E, int NC) {
    __shared__ int h[1024];
    const int t = threadIdx.x;
    for (int c = t; c < NC; c += 1024) h[c] = 0;
    __syncthreads();
    const int e0 = blockIdx.x * PCHUNK;
    int e1 = e0 + PCHUNK; if (e1 > E) e1 = E;
    for (int e = e0 + t; e < e1; e += 1024) atomicAdd(&h[I[e] >> 6], 1);
    __syncthreads();
    for (int c = t; c < NC; c += 1024) if (h[c]) atomicAdd(&coarse_hist[c], h[c]);
}

// ---- K3: exclusive scan of NC (<=1024) counts; init cursors ----
__global__ void __launch_bounds__(1024) k_scan(const int* __restrict__ coarse_hist,
                                               int* __restrict__ coarse_base,
                                               int* __restrict__ gcursor, int NC) {
    __shared__ int sh[1024];
    const int t = threadIdx.x;
    const int v = (t < NC) ? coarse_hist[t] : 0;
    sh[t] = v;
    __syncthreads();
    for (int off = 1; off < 1024; off <<= 1) {
        const int u = (t >= off) ? sh[t - off] : 0;
        __syncthreads();
        sh[t] += u;
        __syncthreads();
    }
    if (t < NC) { coarse_base[t] = sh[t] - v; gcursor[t] = sh[t] - v; }
    if (t == NC - 1) coarse_base[NC] = sh[t];   // = E
}

// ---- K4: partition into 64-row buckets, dense run reservations ----
// record u64: hi32 = bits(w), lo32 = (i & 63) << 16 | j
// Two streaming passes over PCHUNK=8192 (runs ~10.5 rec = 84B, block-
// exclusive lines). 98 blocks x 16 waves; I/J/W3 re-read is L2-cheap.
__global__ void __launch_bounds__(1024) k_partition(
        const int* __restrict__ I, const int* __restrict__ J,
        const float* __restrict__ W3, const float* __restrict__ velocity,
        int* __restrict__ gcursor, ull* __restrict__ part, int E, int NC) {
    __shared__ int hist[1024];
    __shared__ int base[1024];
    const int t = threadIdx.x;
    for (int c = t; c < NC; c += 1024) hist[c] = 0;
    __syncthreads();
    const int e0 = blockIdx.x * PCHUNK;
    int e1 = e0 + PCHUNK; if (e1 > E) e1 = E;

    for (int e = e0 + t; e < e1; e += 1024) atomicAdd(&hist[I[e] >> 6], 1);
    __syncthreads();
    for (int c = t; c < NC; c += 1024) {
        const int cnt = hist[c];
        base[c] = cnt ? atomicAdd(&gcursor[c], cnt) : 0;  // one reservation per (block,bucket)
        hist[c] = 0;                                      // reuse as rank counter
    }
    __syncthreads();
    for (int e = e0 + t; e < e1; e += 1024) {
        const int   i = I[e];
        const int   j = J[e];
        const float w = W3[e] * velocity[j];
        const int   c = i >> 6;
        const int   r = atomicAdd(&hist[c], 1);
        part[(size_t)base[c] + r] = ((ull)__float_as_uint(w) << 32)
                                  | ((ull)((unsigned)(i & 63) << 16) | (unsigned)j);
    }
}

// ---- K5: gather. Block = one 64-row bucket, 8 waves share it. ----
// R6-proven inner loop: records in registers, __shfl broadcast, 8
// independent in_T loads in flight; ds_add_f32 into 64x65 tile.
__global__ void __launch_bounds__(512) k_gather(
        const float* __restrict__ in_T, const ull* __restrict__ part,
        const int* __restrict__ coarse_base, const float* __restrict__ bias,
        float* __restrict__ out, int N) {
    __shared__ float tile[64 * 65];
    const int t    = threadIdx.x;
    const int lane = t & 63;
    const int w    = t >> 6;                 // wave 0..7
    const int c    = blockIdx.x;             // bucket == 64-row stripe

    for (int idx = t; idx < 64 * 65; idx += 512) tile[idx] = 0.f;
    __syncthreads();

    const int beg = coarse_base[c];
    const int end = coarse_base[c + 1];

    for (int base = beg + w * 64; base < end; base += 512) {
        int cc = end - base; if (cc > 64) cc = 64;
        ull rec = 0ull;                          // pad -> w=0, adds 0 to row 0
        if (lane < cc) rec = part[base + lane];
        const int rlo = (int)(unsigned)(rec & 0xffffffffu);
        const int rhi = (int)(unsigned)(rec >> 32);
        for (int k0 = 0; k0 < cc; k0 += 8) {
            float v[8], wv[8]; int li[8];
            #pragma unroll
            for (int u = 0; u < 8; ++u) {
                const int k = k0 + u;
                const unsigned ij = (unsigned)__shfl(rlo, k);
                wv[u] = __uint_as_float((unsigned)__shfl(rhi, k));
                li[u] = (int)((ij >> 16) & 63u);
                const int j = (int)(ij & 0xffffu);
                v[u] = in_T[j * BATCH + lane];   // 8 independent 256B loads
            }
            #pragma unroll
            for (int u = 0; u < 8; ++u) {
                atomicAdd(&tile[li[u] * 65 + lane], v[u] * wv[u]);  // ds_add_f32
            }
        }
    }
    __syncthreads();

    // epilogue: rows [n0, n0+64) -> out[b*N+n] + bias, coalesced per wave
    const int n0  = c * QROWS;
    const int row = t & 63;
    const int bq  = t >> 6;
    const int n = n0 + row;
    if (n < N) {
        const float bv = bias[n];
        for (int b = bq; b < BATCH; b += 8)
            out[(size_t)b * N + n] = tile[row * 65 + b] + bv;
    }
}

// ---- fallback path (ws too small or N doesn't fit u16): direct atomics ----
__global__ void k_edge_scatter_direct(const float* __restrict__ in,
                                      const float* __restrict__ W3,
                                      const float* __restrict__ velocity,
                                      const int* __restrict__ I,
                                      const int* __restrict__ J,
                                      float* __restrict__ out, int N, int E) {
    const int lane = threadIdx.x & 63;
    const long wave   = (long)blockIdx.x * (blockDim.x >> 6) + (threadIdx.x >> 6);
    const long nwaves = (long)gridDim.x * (blockDim.x >> 6);
    for (long base = wave * 64; base < E; base += nwaves * 64) {
        const long e = base + lane;
        int iv = 0, jv = 0; float wvv = 0.f;
        if (e < E) { iv = I[e]; jv = J[e]; wvv = W3[e] * velocity[jv]; }
        const int cnt = (int)((E - base) < 64 ? (E - base) : 64);
        for (int k = 0; k < cnt; ++k) {
            const int   ii = __shfl(iv, k);
            const int   jj = __shfl(jv, k);
            const float wvx = __shfl(wvv, k);
            const float val = in[(size_t)lane * N + jj] * wvx;
            atomicAdd(&out[(size_t)lane * N + ii], val);
        }
    }
}

__global__ void k_add_bias(const float* __restrict__ bias, float* __restrict__ out, int N, int total) {
    int idx = blockIdx.x * blockDim.x + threadIdx.x;
    if (idx < total) out[idx] += bias[idx % N];
}

extern "C" void kernel_launch(void* const* d_in, const int* in_sizes, int n_in,
                              void* d_out, int out_size, void* d_ws, size_t ws_size,
                              hipStream_t stream) {
    const float* inputs   = (const float*)d_in[0];
    const float* W3       = (const float*)d_in[1];
    const float* bias     = (const float*)d_in[2];
    const float* velocity = (const float*)d_in[3];
    const int*   I        = (const int*)d_in[4];
    const int*   J        = (const int*)d_in[5];
    const int E = in_sizes[1];
    const int N = in_sizes[3];
    float* out = (float*)d_out;

    const size_t mat_elems = (size_t)N * BATCH;
    const int NC   = (N + QROWS - 1) / QROWS;       // 64-row buckets
    const int nb_n = (N + 63) / 64;
    const int nb_e = (E + PCHUNK - 1) / PCHUNK;

    // ws: in_T | part | coarse_hist | coarse_base | gcursor
    const size_t need = mat_elems * sizeof(float)
                      + (size_t)E * sizeof(ull)
                      + (size_t)(NC + (NC + 1) + NC) * sizeof(int);

    if (ws_size >= need && N <= 65535 && NC <= 1024) {
        float* in_T        = (float*)d_ws;
        ull*   part        = (ull*)(in_T + mat_elems);
        int*   coarse_hist = (int*)(part + E);
        int*   coarse_base = coarse_hist + NC;
        int*   gcursor     = coarse_base + NC + 1;

        k_prep     <<<nb_n, 256,  0, stream>>>(inputs, in_T, coarse_hist, NC, N);
        k_hist     <<<nb_e, 1024, 0, stream>>>(I, coarse_hist, E, NC);
        k_scan     <<<1,    1024, 0, stream>>>(coarse_hist, coarse_base, gcursor, NC);
        k_partition<<<nb_e, 1024, 0, stream>>>(I, J, W3, velocity, gcursor, part, E, NC);
        k_gather   <<<NC,   512,  0, stream>>>(in_T, part, coarse_base, bias, out, N);
    } else {
        hipMemsetAsync(out, 0, (size_t)out_size * sizeof(float), stream);
        const int waves_needed   = (E + 63) / 64;
        const int scatter_blocks = (waves_needed + 3) / 4;
        k_edge_scatter_direct<<<scatter_blocks, 256, 0, stream>>>(inputs, W3, velocity, I, J, out, N, E);
        k_add_bias<<<(out_size + 255) / 256, 256, 0, stream>>>(bias, out, N, out_size);
    }
}

// Round 5
// 161.804 us; speedup vs baseline: 2.9434x; 2.9434x over previous
//
#include <hip/hip_runtime.h>

// out[b, I[e]] += inputs[b, J[e]] * W3[e] * velocity[J[e]]; out += bias
// R2: per-edge atomics = 204.8MB atomic-path traffic (bound).
// R4: bucket build + gather -> 161.7us; build dominates (scatter evictions).
// R5: nt stores FALSIFIED (WRITE rose). Reverted.
// R6: two-pass counting sort (256-row coarse + finesort) -> 159us. Gather
//     used plain += with wave-exclusive 4-row segments: fast.
// R7: fused filter-gather, shuffle compaction: 445us. Blamed spills: WRONG.
// R8: LDS compaction: 357us. No spills (WRITE==out exactly).
// R9: atomicAdd(shared) vs unsafeAtomicAdd: IDENTICAL -> lowering flavor
//     irrelevant.
// R10: R6-style reg/shfl loop + ds-atomic tile: 368us. Occupancy/structure
//     exonerated. Surviving suspect across ALL slow variants: FP LDS
//     atomics (~240cyc CU-serialized each, back-computed). Int LDS atomics
//     (hist/partition) are proven fast.
// R11: ZERO FP atomics, keep fusion. Per 512-record chunk: bin records by
//     row-octant into 8 LDS bins (int cursor atomics, CAP=512=chunk size ->
//     overflow impossible), then wave w exclusively drains bin w into its
//     own 8 tile rows with R6's reg+shfl+8-loads loop and plain +=.
//     part read once; no finesort; no edges array. 49KB LDS -> 3 blk/CU.

#define BATCH 64
#define QROWS 64              // rows per bucket == rows per gather block
#define PCHUNK 8192           // edges per hist/partition block
#define GCH 512               // records per gather chunk (= block threads)
#define CAP 512               // bin capacity (= GCH -> overflow impossible)

typedef unsigned long long ull;

// ---- K1: transpose inputs [B,N] -> in_T [N,B]; zero histogram ----
__global__ void k_prep(const float* __restrict__ in, float* __restrict__ in_T,
                       int* __restrict__ coarse_hist, int NC, int N) {
    const int gid = blockIdx.x * 256 + threadIdx.x;
    if (gid < NC) coarse_hist[gid] = 0;

    __shared__ float tile[64 * 65];
    const int n0 = blockIdx.x * 64;
    const int t  = threadIdx.x;
    const int x  = t & 63;
    const int r  = t >> 6;
    for (int b = r; b < BATCH; b += 4) {
        float v = 0.f;
        if (n0 + x < N) v = in[(size_t)b * N + n0 + x];
        tile[x * 65 + b] = v;
    }
    __syncthreads();
    for (int xr = r; xr < 64; xr += 4) {
        if (n0 + xr < N) in_T[(size_t)(n0 + xr) * BATCH + x] = tile[xr * 65 + x];
    }
}

// ---- K2: 64-row-bucket histogram (LDS-aggregated, up to 1024 bins) ----
__global__ void __launch_bounds__(1024) k_hist(const int* __restrict__ I,
                                               int* __restrict__ coarse_hist,
                                               int E, int NC) {
    __shared__ int h[1024];
    const int t = threadIdx.x;
    for (int c = t; c < NC; c += 1024) h[c] = 0;
    __syncthreads();
    const int e0 = blockIdx.x * PCHUNK;
    int e1 = e0 + PCHUNK; if (e1 > E) e1 = E;
    for (int e = e0 + t; e < e1; e += 1024) atomicAdd(&h[I[e] >> 6], 1);
    __syncthreads();
    for (int c = t; c < NC; c += 1024) if (h[c]) atomicAdd(&coarse_hist[c], h[c]);
}

// ---- K3: exclusive scan of NC (<=1024) counts; init cursors ----
__global__ void __launch_bounds__(1024) k_scan(const int* __restrict__ coarse_hist,
                                               int* __restrict__ coarse_base,
                                               int* __restrict__ gcursor, int NC) {
    __shared__ int sh[1024];
    const int t = threadIdx.x;
    const int v = (t < NC) ? coarse_hist[t] : 0;
    sh[t] = v;
    __syncthreads();
    for (int off = 1; off < 1024; off <<= 1) {
        const int u = (t >= off) ? sh[t - off] : 0;
        __syncthreads();
        sh[t] += u;
        __syncthreads();
    }
    if (t < NC) { coarse_base[t] = sh[t] - v; gcursor[t] = sh[t] - v; }
    if (t == NC - 1) coarse_base[NC] = sh[t];   // = E
}

// ---- K4: partition into 64-row buckets, dense run reservations ----
// record u64: hi32 = bits(w), lo32 = (i & 63) << 16 | j
__global__ void __launch_bounds__(1024) k_partition(
        const int* __restrict__ I, const int* __restrict__ J,
        const float* __restrict__ W3, const float* __restrict__ velocity,
        int* __restrict__ gcursor, ull* __restrict__ part, int E, int NC) {
    __shared__ int hist[1024];
    __shared__ int base[1024];
    const int t = threadIdx.x;
    for (int c = t; c < NC; c += 1024) hist[c] = 0;
    __syncthreads();
    const int e0 = blockIdx.x * PCHUNK;
    int e1 = e0 + PCHUNK; if (e1 > E) e1 = E;

    for (int e = e0 + t; e < e1; e += 1024) atomicAdd(&hist[I[e] >> 6], 1);
    __syncthreads();
    for (int c = t; c < NC; c += 1024) {
        const int cnt = hist[c];
        base[c] = cnt ? atomicAdd(&gcursor[c], cnt) : 0;  // one reservation per (block,bucket)
        hist[c] = 0;                                      // reuse as rank counter
    }
    __syncthreads();
    for (int e = e0 + t; e < e1; e += 1024) {
        const int   i = I[e];
        const int   j = J[e];
        const float w = W3[e] * velocity[j];
        const int   c = i >> 6;
        const int   r = atomicAdd(&hist[c], 1);
        part[(size_t)base[c] + r] = ((ull)__float_as_uint(w) << 32)
                                  | ((ull)((unsigned)(i & 63) << 16) | (unsigned)j);
    }
}

// ---- K5: gather. Block = one 64-row bucket. Per 512-record chunk: ----
// bin by row-octant (int cursor atomics), then wave w drains bin w into its
// exclusive 8 rows with reg+shfl+8-loads loop and PLAIN += (no FP atomics).
__global__ void __launch_bounds__(512) k_gather(
        const float* __restrict__ in_T, const ull* __restrict__ part,
        const int* __restrict__ coarse_base, const float* __restrict__ bias,
        float* __restrict__ out, int N) {
    __shared__ float tile[64 * 65];
    __shared__ ull   bins[8][CAP];
    __shared__ int   cnt[8];
    const int t    = threadIdx.x;
    const int lane = t & 63;
    const int w    = t >> 6;                 // wave 0..7 = row octant owner
    const int c    = blockIdx.x;             // bucket == 64-row stripe

    for (int idx = t; idx < 64 * 65; idx += 512) tile[idx] = 0.f;

    const int beg = coarse_base[c];
    const int end = coarse_base[c + 1];

    for (int cb = beg; cb < end; cb += GCH) {
        if (t < 8) cnt[t] = 0;
        __syncthreads();                     // reset visible; prev phase B done

        // ---- phase A: place my record into its octant bin (int atomics) ----
        const int e = cb + t;
        if (e < end) {
            const ull rec = part[e];                       // coalesced
            const int bin = (int)(((unsigned)rec >> 19) & 7u);
            const int r = atomicAdd(&cnt[bin], 1);         // native int ds add
            bins[bin][r] = rec;
        }
        __syncthreads();

        // ---- phase B: wave w drains bin w into rows [w*8, w*8+8) ----
        const int cw = cnt[w];
        for (int base = 0; base < cw; base += 64) {
            int cc = cw - base; if (cc > 64) cc = 64;
            ull rec = 0ull;                  // pad -> li=0, wv=0: harmless
            if (lane < cc) rec = bins[w][base + lane];
            const int rlo = (int)(unsigned)(rec & 0xffffffffu);
            const int rhi = (int)(unsigned)(rec >> 32);
            for (int k0 = 0; k0 < cc; k0 += 8) {
                float v[8], wv[8]; int li[8];
                #pragma unroll
                for (int u = 0; u < 8; ++u) {
                    const int k = k0 + u;
                    const unsigned ij = (unsigned)__shfl(rlo, k);
                    wv[u] = __uint_as_float((unsigned)__shfl(rhi, k));
                    li[u] = (int)((ij >> 16) & 7u);      // row within octant
                    const int j = (int)(ij & 0xffffu);
                    v[u] = in_T[j * BATCH + lane];       // 8 independent 256B loads
                }
                #pragma unroll
                for (int u = 0; u < 8; ++u) {
                    tile[(w * 8 + li[u]) * 65 + lane] += v[u] * wv[u];  // plain +=
                }
            }
        }
        __syncthreads();                     // bins/cnt free for next chunk
    }
    __syncthreads();

    // epilogue: rows [n0, n0+64) -> out[b*N+n] + bias, coalesced per wave
    const int n0  = c * QROWS;
    const int row = t & 63;
    const int bq  = t >> 6;
    const int n = n0 + row;
    if (n < N) {
        const float bv = bias[n];
        for (int b = bq; b < BATCH; b += 8)
            out[(size_t)b * N + n] = tile[row * 65 + b] + bv;
    }
}

// ---- fallback path (ws too small or N doesn't fit u16): direct atomics ----
__global__ void k_edge_scatter_direct(const float* __restrict__ in,
                                      const float* __restrict__ W3,
                                      const float* __restrict__ velocity,
                                      const int* __restrict__ I,
                                      const int* __restrict__ J,
                                      float* __restrict__ out, int N, int E) {
    const int lane = threadIdx.x & 63;
    const long wave   = (long)blockIdx.x * (blockDim.x >> 6) + (threadIdx.x >> 6);
    const long nwaves = (long)gridDim.x * (blockDim.x >> 6);
    for (long base = wave * 64; base < E; base += nwaves * 64) {
        const long e = base + lane;
        int iv = 0, jv = 0; float wvv = 0.f;
        if (e < E) { iv = I[e]; jv = J[e]; wvv = W3[e] * velocity[jv]; }
        const int cnt = (int)((E - base) < 64 ? (E - base) : 64);
        for (int k = 0; k < cnt; ++k) {
            const int   ii = __shfl(iv, k);
            const int   jj = __shfl(jv, k);
            const float wvx = __shfl(wvv, k);
            const float val = in[(size_t)lane * N + jj] * wvx;
            atomicAdd(&out[(size_t)lane * N + ii], val);
        }
    }
}

__global__ void k_add_bias(const float* __restrict__ bias, float* __restrict__ out, int N, int total) {
    int idx = blockIdx.x * blockDim.x + threadIdx.x;
    if (idx < total) out[idx] += bias[idx % N];
}

extern "C" void kernel_launch(void* const* d_in, const int* in_sizes, int n_in,
                              void* d_out, int out_size, void* d_ws, size_t ws_size,
                              hipStream_t stream) {
    const float* inputs   = (const float*)d_in[0];
    const float* W3       = (const float*)d_in[1];
    const float* bias     = (const float*)d_in[2];
    const float* velocity = (const float*)d_in[3];
    const int*   I        = (const int*)d_in[4];
    const int*   J        = (const int*)d_in[5];
    const int E = in_sizes[1];
    const int N = in_sizes[3];
    float* out = (float*)d_out;

    const size_t mat_elems = (size_t)N * BATCH;
    const int NC   = (N + QROWS - 1) / QROWS;       // 64-row buckets
    const int nb_n = (N + 63) / 64;
    const int nb_e = (E + PCHUNK - 1) / PCHUNK;

    // ws: in_T | part | coarse_hist | coarse_base | gcursor
    const size_t need = mat_elems * sizeof(float)
                      + (size_t)E * sizeof(ull)
                      + (size_t)(NC + (NC + 1) + NC) * sizeof(int);

    if (ws_size >= need && N <= 65535 && NC <= 1024) {
        float* in_T        = (float*)d_ws;
        ull*   part        = (ull*)(in_T + mat_elems);
        int*   coarse_hist = (int*)(part + E);
        int*   coarse_base = coarse_hist + NC;
        int*   gcursor     = coarse_base + NC + 1;

        k_prep     <<<nb_n, 256,  0, stream>>>(inputs, in_T, coarse_hist, NC, N);
        k_hist     <<<nb_e, 1024, 0, stream>>>(I, coarse_hist, E, NC);
        k_scan     <<<1,    1024, 0, stream>>>(coarse_hist, coarse_base, gcursor, NC);
        k_partition<<<nb_e, 1024, 0, stream>>>(I, J, W3, velocity, gcursor, part, E, NC);
        k_gather   <<<NC,   512,  0, stream>>>(in_T, part, coarse_base, bias, out, N);
    } else {
        hipMemsetAsync(out, 0, (size_t)out_size * sizeof(float), stream);
        const int waves_needed   = (E + 63) / 64;
        const int scatter_blocks = (waves_needed + 3) / 4;
        k_edge_scatter_direct<<<scatter_blocks, 256, 0, stream>>>(inputs, W3, velocity, I, J, out, N, E);
        k_add_bias<<<(out_size + 255) / 256, 256, 0, stream>>>(bias, out, N, out_size);
    }
}

// Round 6
// 148.908 us; speedup vs baseline: 3.1984x; 1.0866x over previous
//
#include <hip/hip_runtime.h>

// out[b, I[e]] += inputs[b, J[e]] * W3[e] * velocity[J[e]]; out += bias
// R2: per-edge global atomics = 204.8MB atomic-path traffic (bound).
// R4: bucket build + gather -> 161.7us; build dominates (scatter evictions).
// R5: nt stores FALSIFIED (WRITE rose). Reverted.
// R6: counting sort + finesort -> 159us (finesort starved, edges roundtrip).
// R7-R9: fused filter-gather variants all ~350-450us. Spill theory and
//     atomic-lowering-flavor theory both falsified by A/B.
// R10: R6-style reg/shfl loop + ds FP atomic tile: 368us.
// R11: wave-exclusive += (zero FP atomics): gather 368 -> 47.5us. CONFIRMED:
//     FP LDS atomics were the poison (~240cyc serialized each). Total 161.8.
// R12: two bottlenecks from R11 counters:
//     (a) gather is LDS-PIPE-bound: ~5-6 LDS ops/record (2 of them
//         ds_bpermute from __shfl). Fix: per-ROW bins (64 bins, int cursor,
//         CAP=32 + overflow list for adversarial rows), drain via UNIFORM
//         ds_read_b64 broadcast into REGISTER acc[8] (static unroll) ->
//         3 LDS ops/record, tile RMW gone; tile aliased over bins, written
//         once for the transposed epilogue. Bin stride 33 (bank-pad).
//     (b) hist/partition at 98 blocks = >half chip idle. Chunk 2048 x 512thr
//         -> 391 blocks; partition single-pass register-stash. Run 84->21B:
//         accept write amplification for 4x occupancy.

#define BATCH 64
#define QROWS 64              // rows per bucket == rows per gather block
#define PCHUNK 2048           // edges per hist/partition block
#define GCH 512               // records per gather chunk (= block threads)
#define BCAP 32               // per-row bin capacity
#define BSTR 33               // padded bin stride (bank-conflict-free)

typedef unsigned long long ull;

// ---- K1: transpose inputs [B,N] -> in_T [N,B]; zero histogram ----
__global__ void k_prep(const float* __restrict__ in, float* __restrict__ in_T,
                       int* __restrict__ coarse_hist, int NC, int N) {
    const int gid = blockIdx.x * 256 + threadIdx.x;
    if (gid < NC) coarse_hist[gid] = 0;

    __shared__ float tile[64 * 65];
    const int n0 = blockIdx.x * 64;
    const int t  = threadIdx.x;
    const int x  = t & 63;
    const int r  = t >> 6;
    for (int b = r; b < BATCH; b += 4) {
        float v = 0.f;
        if (n0 + x < N) v = in[(size_t)b * N + n0 + x];
        tile[x * 65 + b] = v;
    }
    __syncthreads();
    for (int xr = r; xr < 64; xr += 4) {
        if (n0 + xr < N) in_T[(size_t)(n0 + xr) * BATCH + x] = tile[xr * 65 + x];
    }
}

// ---- K2: 64-row-bucket histogram (LDS-aggregated, up to 1024 bins) ----
__global__ void __launch_bounds__(512) k_hist(const int* __restrict__ I,
                                              int* __restrict__ coarse_hist,
                                              int E, int NC) {
    __shared__ int h[1024];
    const int t = threadIdx.x;
    for (int c = t; c < NC; c += 512) h[c] = 0;
    __syncthreads();
    const int e0 = blockIdx.x * PCHUNK;
    int e1 = e0 + PCHUNK; if (e1 > E) e1 = E;
    for (int e = e0 + t; e < e1; e += 512) atomicAdd(&h[I[e] >> 6], 1);
    __syncthreads();
    for (int c = t; c < NC; c += 512) if (h[c]) atomicAdd(&coarse_hist[c], h[c]);
}

// ---- K3: exclusive scan of NC (<=1024) counts; init cursors ----
__global__ void __launch_bounds__(1024) k_scan(const int* __restrict__ coarse_hist,
                                               int* __restrict__ coarse_base,
                                               int* __restrict__ gcursor, int NC) {
    __shared__ int sh[1024];
    const int t = threadIdx.x;
    const int v = (t < NC) ? coarse_hist[t] : 0;
    sh[t] = v;
    __syncthreads();
    for (int off = 1; off < 1024; off <<= 1) {
        const int u = (t >= off) ? sh[t - off] : 0;
        __syncthreads();
        sh[t] += u;
        __syncthreads();
    }
    if (t < NC) { coarse_base[t] = sh[t] - v; gcursor[t] = sh[t] - v; }
    if (t == NC - 1) coarse_base[NC] = sh[t];   // = E
}

// ---- K4: partition into 64-row buckets, single-pass register stash ----
// record u64: hi32 = bits(w), lo32 = (i & 63) << 16 | j
__global__ void __launch_bounds__(512) k_partition(
        const int* __restrict__ I, const int* __restrict__ J,
        const float* __restrict__ W3, const float* __restrict__ velocity,
        int* __restrict__ gcursor, ull* __restrict__ part, int E, int NC) {
    __shared__ int hist[1024];
    __shared__ int base[1024];
    const int t = threadIdx.x;
    for (int c = t; c < NC; c += 512) hist[c] = 0;
    __syncthreads();
    const int e0 = blockIdx.x * PCHUNK;
    int e1 = e0 + PCHUNK; if (e1 > E) e1 = E;

    ull  rec[4];
    int  cb[4];
    int  rk[4];
    bool ok[4];
    #pragma unroll
    for (int u = 0; u < 4; ++u) {
        const int e = e0 + u * 512 + t;
        ok[u] = (e < e1);
        cb[u] = 0; rk[u] = 0; rec[u] = 0ull;
        if (ok[u]) {
            const int   i = I[e];
            const int   j = J[e];
            const float w = W3[e] * velocity[j];
            cb[u] = i >> 6;
            rk[u] = atomicAdd(&hist[cb[u]], 1);     // count IS the rank
            rec[u] = ((ull)__float_as_uint(w) << 32)
                   | ((ull)((unsigned)(i & 63) << 16) | (unsigned)j);
        }
    }
    __syncthreads();
    for (int c = t; c < NC; c += 512) {
        const int cnt = hist[c];
        base[c] = cnt ? atomicAdd(&gcursor[c], cnt) : 0;  // one reservation per (block,bucket)
    }
    __syncthreads();
    #pragma unroll
    for (int u = 0; u < 4; ++u)
        if (ok[u]) part[(size_t)base[cb[u]] + rk[u]] = rec[u];
}

// ---- K5: gather. Block = one 64-row bucket. Per 512-record chunk: ----
// phase A bins records by ROW (64 bins, int cursor, CAP=32 + overflow list);
// phase B: wave w drains rows [w*8,w*8+8) via uniform ds_read_b64 broadcast
// into register acc[8] (static unroll). Tile aliased over bins; written once.
__global__ void __launch_bounds__(512) k_gather(
        const float* __restrict__ in_T, const ull* __restrict__ part,
        const int* __restrict__ coarse_base, const float* __restrict__ bias,
        float* __restrict__ out, int N) {
    __shared__ ull smem[64 * BSTR + GCH];       // bins[64][33] | ovf[512]
    __shared__ int cnt[64];
    __shared__ int ocnt;
    ull* const bins = smem;
    ull* const ovf  = smem + 64 * BSTR;
    float* const tile = (float*)smem;           // 64x65 f32 = 2080 ull < 2624

    const int t    = threadIdx.x;
    const int lane = t & 63;
    const int w    = t >> 6;                    // wave 0..7 = row-octant owner
    const int c    = blockIdx.x;                // bucket == 64-row stripe

    const int beg = coarse_base[c];
    const int end = coarse_base[c + 1];

    float acc[8];
    #pragma unroll
    for (int r = 0; r < 8; ++r) acc[r] = 0.f;

    for (int cb = beg; cb < end; cb += GCH) {
        __syncthreads();                        // prev phase B done
        if (t < 64) cnt[t] = 0;
        if (t == 0) ocnt = 0;
        __syncthreads();

        // ---- phase A: place my record into its row bin (int atomics) ----
        const int e = cb + t;
        if (e < end) {
            const ull rec = part[e];                      // coalesced
            const int li = (int)(((unsigned)rec >> 16) & 63u);
            const int r = atomicAdd(&cnt[li], 1);         // native int ds add
            if (r < BCAP) bins[li * BSTR + r] = rec;
            else          ovf[atomicAdd(&ocnt, 1)] = rec; // structurally safe: ocnt<=GCH
        }
        __syncthreads();

        // ---- phase B: wave w drains its 8 rows; register accumulate ----
        #pragma unroll
        for (int r8 = 0; r8 < 8; ++r8) {
            const int row = w * 8 + r8;
            int n = cnt[row]; if (n > BCAP) n = BCAP;
            const ull* bp = &bins[row * BSTR];
            float a = acc[r8];
            int k = 0;
            for (; k + 4 <= n; k += 4) {
                const ull r0 = bp[k], r1 = bp[k + 1], r2 = bp[k + 2], r3 = bp[k + 3];
                const float v0 = in_T[(int)((unsigned)r0 & 0xffffu) * BATCH + lane];
                const float v1 = in_T[(int)((unsigned)r1 & 0xffffu) * BATCH + lane];
                const float v2 = in_T[(int)((unsigned)r2 & 0xffffu) * BATCH + lane];
                const float v3 = in_T[(int)((unsigned)r3 & 0xffffu) * BATCH + lane];
                a += v0 * __uint_as_float((unsigned)(r0 >> 32));
                a += v1 * __uint_as_float((unsigned)(r1 >> 32));
                a += v2 * __uint_as_float((unsigned)(r2 >> 32));
                a += v3 * __uint_as_float((unsigned)(r3 >> 32));
            }
            for (; k < n; ++k) {
                const ull rr = bp[k];
                a += in_T[(int)((unsigned)rr & 0xffffu) * BATCH + lane]
                   * __uint_as_float((unsigned)(rr >> 32));
            }
            acc[r8] = a;
        }

        // ---- overflow (rare; nonzero only for highly skewed rows) ----
        const int oc = ocnt;
        if (oc > 0) {
            #pragma unroll
            for (int r8 = 0; r8 < 8; ++r8) {
                const int row = w * 8 + r8;
                float a = acc[r8];
                for (int k = 0; k < oc; ++k) {
                    const ull rr = ovf[k];
                    if ((int)(((unsigned)rr >> 16) & 63u) == row)
                        a += in_T[(int)((unsigned)rr & 0xffffu) * BATCH + lane]
                           * __uint_as_float((unsigned)(rr >> 32));
                }
                acc[r8] = a;
            }
        }
    }

    __syncthreads();                            // all bins reads complete
    #pragma unroll
    for (int r8 = 0; r8 < 8; ++r8)
        tile[(w * 8 + r8) * 65 + lane] = acc[r8];
    __syncthreads();

    // epilogue: rows [n0, n0+64) -> out[b*N+n] + bias, coalesced per wave
    const int n0  = c * QROWS;
    const int row = t & 63;
    const int bq  = t >> 6;
    const int n = n0 + row;
    if (n < N) {
        const float bv = bias[n];
        for (int b = bq; b < BATCH; b += 8)
            out[(size_t)b * N + n] = tile[row * 65 + b] + bv;
    }
}

// ---- fallback path (ws too small or N doesn't fit u16): direct atomics ----
__global__ void k_edge_scatter_direct(const float* __restrict__ in,
                                      const float* __restrict__ W3,
                                      const float* __restrict__ velocity,
                                      const int* __restrict__ I,
                                      const int* __restrict__ J,
                                      float* __restrict__ out, int N, int E) {
    const int lane = threadIdx.x & 63;
    const long wave   = (long)blockIdx.x * (blockDim.x >> 6) + (threadIdx.x >> 6);
    const long nwaves = (long)gridDim.x * (blockDim.x >> 6);
    for (long base = wave * 64; base < E; base += nwaves * 64) {
        const long e = base + lane;
        int iv = 0, jv = 0; float wvv = 0.f;
        if (e < E) { iv = I[e]; jv = J[e]; wvv = W3[e] * velocity[jv]; }
        const int cnt = (int)((E - base) < 64 ? (E - base) : 64);
        for (int k = 0; k < cnt; ++k) {
            const int   ii = __shfl(iv, k);
            const int   jj = __shfl(jv, k);
            const float wvx = __shfl(wvv, k);
            const float val = in[(size_t)lane * N + jj] * wvx;
            atomicAdd(&out[(size_t)lane * N + ii], val);
        }
    }
}

__global__ void k_add_bias(const float* __restrict__ bias, float* __restrict__ out, int N, int total) {
    int idx = blockIdx.x * blockDim.x + threadIdx.x;
    if (idx < total) out[idx] += bias[idx % N];
}

extern "C" void kernel_launch(void* const* d_in, const int* in_sizes, int n_in,
                              void* d_out, int out_size, void* d_ws, size_t ws_size,
                              hipStream_t stream) {
    const float* inputs   = (const float*)d_in[0];
    const float* W3       = (const float*)d_in[1];
    const float* bias     = (const float*)d_in[2];
    const float* velocity = (const float*)d_in[3];
    const int*   I        = (const int*)d_in[4];
    const int*   J        = (const int*)d_in[5];
    const int E = in_sizes[1];
    const int N = in_sizes[3];
    float* out = (float*)d_out;

    const size_t mat_elems = (size_t)N * BATCH;
    const int NC   = (N + QROWS - 1) / QROWS;       // 64-row buckets
    const int nb_n = (N + 63) / 64;
    const int nb_e = (E + PCHUNK - 1) / PCHUNK;

    // ws: in_T | part | coarse_hist | coarse_base | gcursor
    const size_t need = mat_elems * sizeof(float)
                      + (size_t)E * sizeof(ull)
                      + (size_t)(NC + (NC + 1) + NC) * sizeof(int);

    if (ws_size >= need && N <= 65535 && NC <= 1024) {
        float* in_T        = (float*)d_ws;
        ull*   part        = (ull*)(in_T + mat_elems);
        int*   coarse_hist = (int*)(part + E);
        int*   coarse_base = coarse_hist + NC;
        int*   gcursor     = coarse_base + NC + 1;

        k_prep     <<<nb_n, 256,  0, stream>>>(inputs, in_T, coarse_hist, NC, N);
        k_hist     <<<nb_e, 512,  0, stream>>>(I, coarse_hist, E, NC);
        k_scan     <<<1,    1024, 0, stream>>>(coarse_hist, coarse_base, gcursor, NC);
        k_partition<<<nb_e, 512,  0, stream>>>(I, J, W3, velocity, gcursor, part, E, NC);
        k_gather   <<<NC,   512,  0, stream>>>(in_T, part, coarse_base, bias, out, N);
    } else {
        hipMemsetAsync(out, 0, (size_t)out_size * sizeof(float), stream);
        const int waves_needed   = (E + 63) / 64;
        const int scatter_blocks = (waves_needed + 3) / 4;
        k_edge_scatter_direct<<<scatter_blocks, 256, 0, stream>>>(inputs, W3, velocity, I, J, out, N, E);
        k_add_bias<<<(out_size + 255) / 256, 256, 0, stream>>>(bias, out, N, out_size);
    }
}